// Round 4
// baseline (25721.518 us; speedup 1.0000x reference)
//
#include <hip/hip_runtime.h>
#include <hip/hip_bf16.h>
#include <math.h>

#define Bsz  64
#define Hd   2048
#define G3   6144
#define MELn 130
#define CHn  12
#define RHYn 3
#define Tn   32

__device__ __forceinline__ float sigf(float x) { return 1.0f / (1.0f + expf(-x)); }

// ---------------------------------------------------------------------------
// prep: transpose z1/z2 -> [128][64], condition -> [T][CH][64], init feedback idx
// ---------------------------------------------------------------------------
__global__ void prep_misc(const float* __restrict__ z1, const float* __restrict__ z2,
                          const float* __restrict__ cond,
                          float* __restrict__ z1t, float* __restrict__ z2t,
                          float* __restrict__ cond_t, int* __restrict__ rhy_idx,
                          int* __restrict__ mel_idx)
{
    int idx = blockIdx.x * 256 + threadIdx.x;
    if (idx < 128 * Bsz) {
        int j = idx >> 6, b = idx & 63;
        z1t[idx] = z1[b * 128 + j];
        z2t[idx] = z2[b * 128 + j];
    }
    if (idx < Tn * CHn * Bsz) {
        int t = idx / (CHn * Bsz);
        int r = idx - t * CHn * Bsz;
        int j = r >> 6, b = r & 63;
        cond_t[idx] = cond[b * (Tn * CHn) + t * CHn + j];
    }
    if (idx < Bsz) { rhy_idx[idx] = RHYn - 1; mel_idx[idx] = MELn - 1; }
}

// ---------------------------------------------------------------------------
__global__ __launch_bounds__(256) void init_h_k(
    const float* __restrict__ z1t, const float* __restrict__ z2t,
    const float* __restrict__ wi0, const float* __restrict__ bi0,
    const float* __restrict__ wi1, const float* __restrict__ bi1,
    float* __restrict__ h0_out, float* __restrict__ h1_out)
{
    int lane = threadIdx.x & 63, wave = threadIdx.x >> 6;
    int j = blockIdx.x * 4 + wave;
    int which = blockIdx.y;
    const float* zt = which ? z1t : z2t;
    const float* wi = which ? wi1 : wi0;
    const float* bi = which ? bi1 : bi0;
    float* outh = which ? h1_out : h0_out;
    const float4* w4 = (const float4*)(wi + (size_t)j * 128);
    float acc = 0.f;
#pragma unroll 8
    for (int i = 0; i < 32; i++) {
        float4 w = w4[i];
        int k = i * 4;
        acc = fmaf(zt[(k + 0) * 64 + lane], w.x, acc);
        acc = fmaf(zt[(k + 1) * 64 + lane], w.y, acc);
        acc = fmaf(zt[(k + 2) * 64 + lane], w.z, acc);
        acc = fmaf(zt[(k + 3) * 64 + lane], w.w, acc);
    }
    outh[j * 64 + lane] = tanhf(acc + bi[j]);
}

// ---------------------------------------------------------------------------
__global__ __launch_bounds__(256) void gi_const_k(
    const float* __restrict__ z1t, const float* __restrict__ z2t,
    const float* __restrict__ w_ih0, const float* __restrict__ b_ih0,
    const float* __restrict__ w_ih1, const float* __restrict__ b_ih1,
    float* __restrict__ gi0c, float* __restrict__ gi1c)
{
    int lane = threadIdx.x & 63, wave = threadIdx.x >> 6;
    int row = blockIdx.x * 4 + wave;
    int which = blockIdx.y;
    const float* zt; const float* w; float acc; float* dst;
    if (which == 0) { zt = z2t; w = w_ih0 + (size_t)row * 131 + RHYn;          acc = b_ih0[row]; dst = gi0c; }
    else            { zt = z1t; w = w_ih1 + (size_t)row * 273 + (MELn + RHYn); acc = b_ih1[row]; dst = gi1c; }
#pragma unroll 4
    for (int i = 0; i < 128; i++) acc = fmaf(zt[i * 64 + lane], w[i], acc);
    dst[(size_t)row * 64 + lane] = acc;
}

// ---------------------------------------------------------------------------
// 64x64 tile transpose: in [R][C] -> out [C][Rout]
// ---------------------------------------------------------------------------
__device__ __forceinline__ void transpose_body(
    const float* __restrict__ in, float* __restrict__ out, int R, int C, int Rout,
    int bx, int by, float* tile)
{
    int c0 = bx * 64, r0 = by * 64;
    int t = threadIdx.x;
    int cl = t & 63, rw = t >> 6;
#pragma unroll
    for (int i = 0; i < 16; ++i) {
        int rl = rw + i * 4;
        int r = r0 + rl, c = c0 + cl;
        float v = (r < R && c < C) ? in[(size_t)r * C + c] : 0.f;
        tile[rl * 65 + cl] = v;
    }
    __syncthreads();
#pragma unroll
    for (int i = 0; i < 16; ++i) {
        int c_loc = rw + i * 4;
        int r_loc = cl;
        int oc = c0 + c_loc, orow = r0 + r_loc;
        if (oc < C && orow < R)
            out[(size_t)oc * Rout + orow] = tile[r_loc * 65 + c_loc];
    }
}

__global__ __launch_bounds__(256) void transpose4_k(
    const float* __restrict__ a, const float* __restrict__ b,
    const float* __restrict__ c, const float* __restrict__ d,
    float* __restrict__ oa, float* __restrict__ ob,
    float* __restrict__ oc, float* __restrict__ od)
{
    __shared__ float tile[64 * 65];
    const float* in; float* out;
    switch (blockIdx.z) {
        case 0: in = a; out = oa; break;
        case 1: in = b; out = ob; break;
        case 2: in = c; out = oc; break;
        default: in = d; out = od; break;
    }
    transpose_body(in, out, G3, Hd, G3, blockIdx.x, blockIdx.y, tile);
}

__global__ __launch_bounds__(256) void transpose1_k(
    const float* __restrict__ in, float* __restrict__ out, int R, int C, int Rout)
{
    __shared__ float tile[64 * 65];
    transpose_body(in, out, R, C, Rout, blockIdx.x, blockIdx.y, tile);
}

// ---------------------------------------------------------------------------
// Fused step kernel.
// MODE 0: rhythm  — mm(WT0,h) + gates + (last block) 3-class logits/argmax
// MODE 1: melody1 — mm(WT1,ha) + gates(one-hot + rank-15 corrections)
// MODE 2: melody2 — fused mm(WTi2,ha)+(WTh2,hb) + gates
// mm: tiles of 128 rows, thread = 8 rows x 4 batch; k-split over blockIdx.y.
// Reduction fused via per-32-hidden-subgroup done-counters (target 48).
// ---------------------------------------------------------------------------
template<int MODE>
__global__ __launch_bounds__(256) void step_k(
    const float* __restrict__ WTa, const float* __restrict__ xa,
    const float* __restrict__ WTb, const float* __restrict__ xb,
    float* __restrict__ part, int* __restrict__ cnt,
    const float* __restrict__ gi_c, const float* __restrict__ w_ih,
    const float* __restrict__ biasA, const float* __restrict__ biasB,
    float* __restrict__ h_out, int* __restrict__ fb_idx,
    const float* __restrict__ rlo_in, const float* __restrict__ cond,
    const float* __restrict__ wo0, const float* __restrict__ bo0,
    float* __restrict__ rlo_out)
{
    constexpr int SLOTS = (MODE == 2) ? 8 : 16;
    constexpr int KC    = (MODE == 2) ? 256 : 128;
    constexpr int PSTR  = (MODE == 2) ? 786432 : 393216;

    __shared__ float xs[128 * 64];
    __shared__ int flg[4];
    __shared__ int flg2;

    int tid = threadIdx.x;
    int tile = blockIdx.x, slot = blockIdx.y;
    const float* WT; const float* x; int tLoc;
    if (MODE == 2 && tile >= 48) { WT = WTb; x = xb; tLoc = tile - 48; }
    else                         { WT = WTa; x = xa; tLoc = tile; }

    int rg = tid & 15, bg = tid >> 4;
    int r0 = tLoc * 128 + rg * 8;
    int b0 = bg * 4;

    float acc[8][4];
#pragma unroll
    for (int i = 0; i < 8; i++)
#pragma unroll
        for (int j = 0; j < 4; j++) acc[i][j] = 0.f;

    for (int ph = 0; ph < KC / 128; ++ph) {
        int kp = slot * KC + ph * 128;
        __syncthreads();
        {
            const float4* src = (const float4*)(x + (size_t)kp * 64);
            float4* dst = (float4*)xs;
#pragma unroll
            for (int i = 0; i < 8; i++) dst[tid + i * 256] = src[tid + i * 256];
        }
        __syncthreads();
        const float* wp = WT + (size_t)kp * G3 + r0;
#pragma unroll 4
        for (int k = 0; k < 128; ++k) {
            float4 xv = *(const float4*)&xs[k * 64 + b0];
            float w[8];
            *(float4*)&w[0] = *(const float4*)wp;
            *(float4*)&w[4] = *(const float4*)(wp + 4);
            wp += G3;
#pragma unroll
            for (int i = 0; i < 8; i++) {
                acc[i][0] = fmaf(w[i], xv.x, acc[i][0]);
                acc[i][1] = fmaf(w[i], xv.y, acc[i][1]);
                acc[i][2] = fmaf(w[i], xv.z, acc[i][2]);
                acc[i][3] = fmaf(w[i], xv.w, acc[i][3]);
            }
        }
    }

    // store partials
    {
        size_t base = (size_t)slot * PSTR + b0;
#pragma unroll
        for (int i = 0; i < 8; i++) {
            int prow = tile * 128 + rg * 8 + i;
            *(float4*)&part[base + (size_t)prow * 64] = *(float4*)acc[i];
        }
    }

    // done-counter protocol: block covers 4 subgroups of 32 hidden units
    __threadfence();
    __syncthreads();
    int lt = tile & 15;   // position within gate-section
    if (tid < 4) {
        int rc = atomicAdd(&cnt[lt * 4 + tid], 1);
        flg[tid] = (rc == 47) ? 1 : 0;
    }
    __syncthreads();

    for (int s4 = 0; s4 < 4; ++s4) {
        if (!flg[s4]) continue;                 // block-uniform
        __threadfence();                        // acquire
        int sg = lt * 4 + s4;                   // subgroup 0..63
        int q = tid >> 4, bq = tid & 15;
        int b4 = bq * 4;
        const float* hprev = (MODE == 2) ? xb : xa;
#pragma unroll
        for (int rr = 0; rr < 2; ++rr) {
            int j = sg * 32 + q * 2 + rr;       // hidden unit
            if (MODE == 2) {
                float4 air = {0,0,0,0}, aiz = {0,0,0,0}, ain = {0,0,0,0};
                float4 ahr = {0,0,0,0}, ahz = {0,0,0,0}, ahn = {0,0,0,0};
#pragma unroll
                for (int s = 0; s < SLOTS; s++) {
                    const float* pp = part + (size_t)s * PSTR + (size_t)j * 64 + b4;
                    float4 v;
                    v = *(const float4*)(pp + 0 * 64);        air.x += v.x; air.y += v.y; air.z += v.z; air.w += v.w;
                    v = *(const float4*)(pp + 2048 * 64);     aiz.x += v.x; aiz.y += v.y; aiz.z += v.z; aiz.w += v.w;
                    v = *(const float4*)(pp + 4096 * 64);     ain.x += v.x; ain.y += v.y; ain.z += v.z; ain.w += v.w;
                    v = *(const float4*)(pp + 6144 * 64);     ahr.x += v.x; ahr.y += v.y; ahr.z += v.z; ahr.w += v.w;
                    v = *(const float4*)(pp + 8192 * 64);     ahz.x += v.x; ahz.y += v.y; ahz.z += v.z; ahz.w += v.w;
                    v = *(const float4*)(pp + 10240 * 64);    ahn.x += v.x; ahn.y += v.y; ahn.z += v.z; ahn.w += v.w;
                }
                float bir = biasA[j], biz = biasA[j + 2048], bin = biasA[j + 4096];
                float bhr = biasB[j], bhz = biasB[j + 2048], bhn = biasB[j + 4096];
                float4 outv;
                const float* ai = (const float*)&air; const float* az_ = (const float*)&aiz;
                const float* an_ = (const float*)&ain; const float* hr = (const float*)&ahr;
                const float* hz = (const float*)&ahz; const float* hn = (const float*)&ahn;
                float* ov = (float*)&outv;
#pragma unroll
                for (int c = 0; c < 4; c++) {
                    int b = b4 + c;
                    float rg_ = sigf(ai[c] + bir + hr[c] + bhr);
                    float ug  = sigf(az_[c] + biz + hz[c] + bhz);
                    float ng  = tanhf(an_[c] + bin + rg_ * (hn[c] + bhn));
                    float hp = hprev[(size_t)j * 64 + b];
                    ov[c] = (1.f - ug) * ng + ug * hp;
                }
                *(float4*)&h_out[(size_t)j * 64 + b4] = outv;
            } else {
                float4 ar = {0,0,0,0}, az = {0,0,0,0}, an = {0,0,0,0};
#pragma unroll
                for (int s = 0; s < SLOTS; s++) {
                    const float* pp = part + (size_t)s * PSTR + (size_t)j * 64 + b4;
                    float4 v;
                    v = *(const float4*)(pp + 0 * 64);     ar.x += v.x; ar.y += v.y; ar.z += v.z; ar.w += v.w;
                    v = *(const float4*)(pp + 2048 * 64);  az.x += v.x; az.y += v.y; az.z += v.z; az.w += v.w;
                    v = *(const float4*)(pp + 4096 * 64);  an.x += v.x; an.y += v.y; an.z += v.z; an.w += v.w;
                }
                float4 g0 = *(const float4*)&gi_c[(size_t)j * 64 + b4];
                float4 g1 = *(const float4*)&gi_c[(size_t)(j + 2048) * 64 + b4];
                float4 g2 = *(const float4*)&gi_c[(size_t)(j + 4096) * 64 + b4];
                float bhr = biasA[j], bhz = biasA[j + 2048], bhn = biasA[j + 4096];
                const float* arp = (const float*)&ar; const float* azp = (const float*)&az;
                const float* anp = (const float*)&an;
                const float* g0p = (const float*)&g0; const float* g1p = (const float*)&g1;
                const float* g2p = (const float*)&g2;
                float4 outv; float* ov = (float*)&outv;
                if (MODE == 0) {
                    const int WS = 131;
#pragma unroll
                    for (int c = 0; c < 4; c++) {
                        int b = b4 + c;
                        int oi = fb_idx[b];
                        float gir = g0p[c] + w_ih[(size_t)j * WS + oi];
                        float giz = g1p[c] + w_ih[(size_t)(j + 2048) * WS + oi];
                        float gin = g2p[c] + w_ih[(size_t)(j + 4096) * WS + oi];
                        float rg_ = sigf(gir + arp[c] + bhr);
                        float ug  = sigf(giz + azp[c] + bhz);
                        float ng  = tanhf(gin + rg_ * (anp[c] + bhn));
                        float hp = hprev[(size_t)j * 64 + b];
                        ov[c] = (1.f - ug) * ng + ug * hp;
                    }
                } else {
                    const int WS = 273;
                    const float* w0 = w_ih + (size_t)j * WS;
                    const float* w1 = w_ih + (size_t)(j + 2048) * WS;
                    const float* w2 = w_ih + (size_t)(j + 4096) * WS;
#pragma unroll
                    for (int c = 0; c < 4; c++) {
                        int b = b4 + c;
                        int oi = fb_idx[b];
                        float r0v = rlo_in[b * 3 + 0], r1v = rlo_in[b * 3 + 1], r2v = rlo_in[b * 3 + 2];
                        float gir = g0p[c] + w0[oi] + r0v * w0[130] + r1v * w0[131] + r2v * w0[132];
                        float giz = g1p[c] + w1[oi] + r0v * w1[130] + r1v * w1[131] + r2v * w1[132];
                        float gin = g2p[c] + w2[oi] + r0v * w2[130] + r1v * w2[131] + r2v * w2[132];
#pragma unroll
                        for (int qq = 0; qq < 12; qq++) {
                            float cdv = cond[qq * 64 + b];
                            gir = fmaf(cdv, w0[261 + qq], gir);
                            giz = fmaf(cdv, w1[261 + qq], giz);
                            gin = fmaf(cdv, w2[261 + qq], gin);
                        }
                        float rg_ = sigf(gir + arp[c] + bhr);
                        float ug  = sigf(giz + azp[c] + bhz);
                        float ng  = tanhf(gin + rg_ * (anp[c] + bhn));
                        float hp = hprev[(size_t)j * 64 + b];
                        ov[c] = (1.f - ug) * ng + ug * hp;
                    }
                }
                *(float4*)&h_out[(size_t)j * 64 + b4] = outv;
            }
        }

        if (MODE == 0) {
            __threadfence();
            if (tid == 0) {
                int rc2 = atomicAdd(&cnt[64], 1);
                flg2 = (rc2 == 63) ? 1 : 0;
            }
            __syncthreads();
            if (flg2) {
                __threadfence();
                // 3-class logits + log_softmax + argmax (single block tail)
                int b = tid & 63, w = tid >> 6;
                float a0 = 0.f, a1 = 0.f, a2 = 0.f;
                int k0 = w * 512;
#pragma unroll 4
                for (int k = 0; k < 512; k += 4) {
                    float4 wv0 = *(const float4*)&wo0[k0 + k];
                    float4 wv1 = *(const float4*)&wo0[2048 + k0 + k];
                    float4 wv2 = *(const float4*)&wo0[4096 + k0 + k];
                    float h0 = h_out[(size_t)(k0 + k + 0) * 64 + b];
                    float h1 = h_out[(size_t)(k0 + k + 1) * 64 + b];
                    float h2 = h_out[(size_t)(k0 + k + 2) * 64 + b];
                    float h3 = h_out[(size_t)(k0 + k + 3) * 64 + b];
                    a0 = fmaf(h0, wv0.x, a0); a0 = fmaf(h1, wv0.y, a0); a0 = fmaf(h2, wv0.z, a0); a0 = fmaf(h3, wv0.w, a0);
                    a1 = fmaf(h0, wv1.x, a1); a1 = fmaf(h1, wv1.y, a1); a1 = fmaf(h2, wv1.z, a1); a1 = fmaf(h3, wv1.w, a1);
                    a2 = fmaf(h0, wv2.x, a2); a2 = fmaf(h1, wv2.y, a2); a2 = fmaf(h2, wv2.z, a2); a2 = fmaf(h3, wv2.w, a2);
                }
                xs[(w * 3 + 0) * 64 + b] = a0;
                xs[(w * 3 + 1) * 64 + b] = a1;
                xs[(w * 3 + 2) * 64 + b] = a2;
                __syncthreads();
                if (w == 0) {
                    float l0 = xs[0 * 64 + b] + xs[3 * 64 + b] + xs[6 * 64 + b] + xs[9 * 64 + b] + bo0[0];
                    float l1 = xs[1 * 64 + b] + xs[4 * 64 + b] + xs[7 * 64 + b] + xs[10 * 64 + b] + bo0[1];
                    float l2 = xs[2 * 64 + b] + xs[5 * 64 + b] + xs[8 * 64 + b] + xs[11 * 64 + b] + bo0[2];
                    int am; float mx;
                    if (l0 >= l1 && l0 >= l2) { am = 0; mx = l0; }
                    else if (l1 >= l2)        { am = 1; mx = l1; }
                    else                      { am = 2; mx = l2; }
                    float s = expf(l0 - mx) + expf(l1 - mx) + expf(l2 - mx);
                    float ls = logf(s);
                    rlo_out[b * 3 + 0] = l0 - mx - ls;
                    rlo_out[b * 3 + 1] = l1 - mx - ls;
                    rlo_out[b * 3 + 2] = l2 - mx - ls;
                    fb_idx[b] = am;
                }
                __syncthreads();
            }
        }
    }
}

// ---------------------------------------------------------------------------
// melody logits (130x64 from 2048) + fused log_softmax + argmax
// grid (2,16): 2 row-tiles (clamped), 16 k-slots; last block does softmax.
// ---------------------------------------------------------------------------
__global__ __launch_bounds__(256) void mel3_k(
    const float* __restrict__ WTo1, const float* __restrict__ hb,
    float* __restrict__ part, int* __restrict__ cnt,
    const float* __restrict__ bo1, float* __restrict__ outp, int t,
    int* __restrict__ mel_idx)
{
    __shared__ float xs[132 * 64];
    __shared__ int flgL;
    int tid = threadIdx.x;
    int tile = blockIdx.x, slot = blockIdx.y;
    int rg = tid & 15, bg = tid >> 4;
    int r0 = tile * 128 + rg * 8;
    int b0 = bg * 4;
    int kp = slot * 128;

    float acc[8][4];
#pragma unroll
    for (int i = 0; i < 8; i++)
#pragma unroll
        for (int j = 0; j < 4; j++) acc[i][j] = 0.f;

    __syncthreads();
    {
        const float4* src = (const float4*)(hb + (size_t)kp * 64);
        float4* dst = (float4*)xs;
#pragma unroll
        for (int i = 0; i < 8; i++) dst[tid + i * 256] = src[tid + i * 256];
    }
    __syncthreads();

    bool fast = (r0 + 7 < MELn);
    for (int k = 0; k < 128; ++k) {
        float4 xv = *(const float4*)&xs[k * 64 + b0];
        const float* wrow = WTo1 + (size_t)(kp + k) * 132;
        float w[8];
        if (fast) {
            *(float4*)&w[0] = *(const float4*)(wrow + r0);
            *(float4*)&w[4] = *(const float4*)(wrow + r0 + 4);
        } else {
#pragma unroll
            for (int i = 0; i < 8; i++) {
                int rc = r0 + i; if (rc > MELn - 1) rc = MELn - 1;
                w[i] = wrow[rc];
            }
        }
#pragma unroll
        for (int i = 0; i < 8; i++) {
            acc[i][0] = fmaf(w[i], xv.x, acc[i][0]);
            acc[i][1] = fmaf(w[i], xv.y, acc[i][1]);
            acc[i][2] = fmaf(w[i], xv.z, acc[i][2]);
            acc[i][3] = fmaf(w[i], xv.w, acc[i][3]);
        }
    }
#pragma unroll
    for (int i = 0; i < 8; i++) {
        int prow = r0 + i; if (prow > MELn - 1) prow = MELn - 1;  // benign dup (same value)
        *(float4*)&part[(size_t)slot * 8320 + (size_t)prow * 64 + b0] = *(float4*)acc[i];
    }

    __threadfence();
    __syncthreads();
    if (tid == 0) {
        int rc = atomicAdd(cnt, 1);
        flgL = (rc == 31) ? 1 : 0;
    }
    __syncthreads();
    if (flgL) {
        __threadfence();
        int q = tid >> 6, b = tid & 63;
#pragma unroll 4
        for (int i = 0; i < 33; i++) {
            int c = q + 4 * i;
            if (c < 132) {
                float l = -1e30f;
                if (c < MELn) {
                    l = bo1[c];
#pragma unroll
                    for (int s = 0; s < 16; s++) l += part[(size_t)s * 8320 + (size_t)c * 64 + b];
                }
                xs[c * 64 + b] = l;
            }
        }
        __syncthreads();
        if (tid < 64) {
            int b2 = tid;
            float mx = -1e30f; int am = 0;
            for (int c = 0; c < MELn; c++) {
                float v = xs[c * 64 + b2];
                if (v > mx) { mx = v; am = c; }
            }
            float sum = 0.f;
            for (int c = 0; c < MELn; c++) sum += expf(xs[c * 64 + b2] - mx);
            float ls = logf(sum);
            for (int c = 0; c < MELn; c++)
                outp[(size_t)b2 * (Tn * MELn) + t * MELn + c] = xs[c * 64 + b2] - mx - ls;
            mel_idx[b2] = am;
        }
    }
}

// ---------------------------------------------------------------------------
extern "C" void kernel_launch(void* const* d_in, const int* in_sizes, int n_in,
                              void* d_out, int out_size, void* d_ws, size_t ws_size,
                              hipStream_t stream)
{
    (void)in_sizes; (void)n_in; (void)out_size; (void)ws_size;
    const float* z1    = (const float*)d_in[0];
    const float* z2    = (const float*)d_in[1];
    const float* cond  = (const float*)d_in[2];
    const float* w_ih0 = (const float*)d_in[3];
    const float* w_hh0 = (const float*)d_in[4];
    const float* b_ih0 = (const float*)d_in[5];
    const float* b_hh0 = (const float*)d_in[6];
    const float* w_ih1 = (const float*)d_in[7];
    const float* w_hh1 = (const float*)d_in[8];
    const float* b_ih1 = (const float*)d_in[9];
    const float* b_hh1 = (const float*)d_in[10];
    const float* w_ih2 = (const float*)d_in[11];
    const float* w_hh2 = (const float*)d_in[12];
    const float* b_ih2 = (const float*)d_in[13];
    const float* b_hh2 = (const float*)d_in[14];
    const float* wi0   = (const float*)d_in[15];
    const float* bi0   = (const float*)d_in[16];
    const float* wo0   = (const float*)d_in[17];
    const float* bo0   = (const float*)d_in[18];
    const float* wi1   = (const float*)d_in[19];
    const float* bi1   = (const float*)d_in[20];
    const float* wo1   = (const float*)d_in[21];
    const float* bo1   = (const float*)d_in[22];
    float* outp = (float*)d_out;
    float* ws = (float*)d_ws;

    // workspace layout (floats), ~232 MB
    size_t off = 0;
    float* WT0  = ws + off; off += 12582912;   // w_hh0^T [2048][6144]
    float* WT1  = ws + off; off += 12582912;   // w_hh1^T
    float* WTi2 = ws + off; off += 12582912;   // w_ih2^T
    float* WTh2 = ws + off; off += 12582912;   // w_hh2^T
    float* WTo1 = ws + off; off += 270336;     // wo1^T [2048][132]
    float* part = ws + off; off += 6291456;    // k-split partials (25 MB)
    float* hR[2] = { ws + off, ws + off + 131072 }; off += 262144;
    float* hA[2] = { ws + off, ws + off + 131072 }; off += 262144;
    float* hB[2] = { ws + off, ws + off + 131072 }; off += 262144;
    float* gi0c   = ws + off; off += 393216;
    float* gi1c   = ws + off; off += 393216;
    float* rlo    = ws + off; off += 6144;     // [32][64][3]
    float* cond_t = ws + off; off += 24576;
    float* z1t    = ws + off; off += 8192;
    float* z2t    = ws + off; off += 8192;
    int* rhy_idx  = (int*)(ws + off); off += 64;
    int* mel_idx  = (int*)(ws + off); off += 64;
    int* cntBase  = (int*)(ws + off); off += 8192;   // counters, zeroed below

    int* cntR  = cntBase;            // 32 x 80 (64 subgroup + 1 final)
    int* cntM1 = cntBase + 2560;     // 32 x 80
    int* cntM2 = cntBase + 5120;     // 32 x 80
    int* cntM3 = cntBase + 7680;     // 32 x 16

    hipMemsetAsync(cntBase, 0, 8192 * sizeof(int), stream);

    // ---- pre-pass ----
    prep_misc<<<96, 256, 0, stream>>>(z1, z2, cond, z1t, z2t, cond_t, rhy_idx, mel_idx);
    init_h_k<<<dim3(Hd / 4, 2), 256, 0, stream>>>(z1t, z2t, wi0, bi0, wi1, bi1, hR[0], hA[0]);
    gi_const_k<<<dim3(G3 / 4, 2), 256, 0, stream>>>(z1t, z2t, w_ih0, b_ih0, w_ih1, b_ih1, gi0c, gi1c);
    transpose4_k<<<dim3(32, 96, 4), 256, 0, stream>>>(w_hh0, w_hh1, w_ih2, w_hh2,
                                                      WT0, WT1, WTi2, WTh2);
    transpose1_k<<<dim3(32, 3), 256, 0, stream>>>(wo1, WTo1, MELn, Hd, 132);

    // ---- rhythm decoder: 1 kernel per step ----
    for (int s = 0; s < Tn; s++) {
        step_k<0><<<dim3(48, 16), 256, 0, stream>>>(
            WT0, hR[s & 1], nullptr, nullptr, part, cntR + s * 80,
            gi0c, w_ih0, b_hh0, nullptr, hR[(s + 1) & 1], rhy_idx,
            nullptr, nullptr, wo0, bo0, rlo + s * 192);
    }

    // ---- melody decoder: 3 kernels per step ----
    for (int t = 0; t < Tn; t++) {
        const float* ha_in = hA[t & 1];
        float* ha_out = hA[(t + 1) & 1];
        step_k<1><<<dim3(48, 16), 256, 0, stream>>>(
            WT1, ha_in, nullptr, nullptr, part, cntM1 + t * 80,
            gi1c, w_ih1, b_hh1, nullptr, ha_out, mel_idx,
            rlo + t * 192, cond_t + t * (CHn * Bsz), nullptr, nullptr, nullptr);
        const float* hb_in = (t == 0) ? (const float*)ha_out : (const float*)hB[t & 1];
        float* hb_out = hB[(t + 1) & 1];
        step_k<2><<<dim3(96, 8), 256, 0, stream>>>(
            WTi2, ha_out, WTh2, hb_in, part, cntM2 + t * 80,
            nullptr, nullptr, b_ih2, b_hh2, hb_out, nullptr,
            nullptr, nullptr, nullptr, nullptr, nullptr);
        mel3_k<<<dim3(2, 16), 256, 0, stream>>>(WTo1, hb_out, part, cntM3 + t * 16,
                                                bo1, outp, t, mel_idx);
    }
}

// Round 5
// 12299.678 us; speedup vs baseline: 2.0912x; 2.0912x over previous
//
#include <hip/hip_runtime.h>
#include <hip/hip_bf16.h>
#include <math.h>

#define Bsz  64
#define Hd   2048
#define G3   6144
#define MELn 130
#define CHn  12
#define RHYn 3
#define Tn   32

__device__ __forceinline__ float sigf(float x) { return 1.0f / (1.0f + expf(-x)); }

// ---------------------------------------------------------------------------
// prep: transpose z1/z2 -> [128][64], condition -> [T][CH][64], init feedback idx
// ---------------------------------------------------------------------------
__global__ void prep_misc(const float* __restrict__ z1, const float* __restrict__ z2,
                          const float* __restrict__ cond,
                          float* __restrict__ z1t, float* __restrict__ z2t,
                          float* __restrict__ cond_t, int* __restrict__ rhy_idx,
                          int* __restrict__ mel_idx)
{
    int idx = blockIdx.x * 256 + threadIdx.x;
    if (idx < 128 * Bsz) {
        int j = idx >> 6, b = idx & 63;
        z1t[idx] = z1[b * 128 + j];
        z2t[idx] = z2[b * 128 + j];
    }
    if (idx < Tn * CHn * Bsz) {
        int t = idx / (CHn * Bsz);
        int r = idx - t * CHn * Bsz;
        int j = r >> 6, b = r & 63;
        cond_t[idx] = cond[b * (Tn * CHn) + t * CHn + j];
    }
    if (idx < Bsz) { rhy_idx[idx] = RHYn - 1; mel_idx[idx] = MELn - 1; }
}

// ---------------------------------------------------------------------------
__global__ __launch_bounds__(256) void init_h_k(
    const float* __restrict__ z1t, const float* __restrict__ z2t,
    const float* __restrict__ wi0, const float* __restrict__ bi0,
    const float* __restrict__ wi1, const float* __restrict__ bi1,
    float* __restrict__ h0_out, float* __restrict__ h1_out)
{
    int lane = threadIdx.x & 63, wave = threadIdx.x >> 6;
    int j = blockIdx.x * 4 + wave;
    int which = blockIdx.y;
    const float* zt = which ? z1t : z2t;
    const float* wi = which ? wi1 : wi0;
    const float* bi = which ? bi1 : bi0;
    float* outh = which ? h1_out : h0_out;
    const float4* w4 = (const float4*)(wi + (size_t)j * 128);
    float acc = 0.f;
#pragma unroll 8
    for (int i = 0; i < 32; i++) {
        float4 w = w4[i];
        int k = i * 4;
        acc = fmaf(zt[(k + 0) * 64 + lane], w.x, acc);
        acc = fmaf(zt[(k + 1) * 64 + lane], w.y, acc);
        acc = fmaf(zt[(k + 2) * 64 + lane], w.z, acc);
        acc = fmaf(zt[(k + 3) * 64 + lane], w.w, acc);
    }
    outh[j * 64 + lane] = tanhf(acc + bi[j]);
}

// ---------------------------------------------------------------------------
__global__ __launch_bounds__(256) void gi_const_k(
    const float* __restrict__ z1t, const float* __restrict__ z2t,
    const float* __restrict__ w_ih0, const float* __restrict__ b_ih0,
    const float* __restrict__ w_ih1, const float* __restrict__ b_ih1,
    float* __restrict__ gi0c, float* __restrict__ gi1c)
{
    int lane = threadIdx.x & 63, wave = threadIdx.x >> 6;
    int row = blockIdx.x * 4 + wave;
    int which = blockIdx.y;
    const float* zt; const float* w; float acc; float* dst;
    if (which == 0) { zt = z2t; w = w_ih0 + (size_t)row * 131 + RHYn;          acc = b_ih0[row]; dst = gi0c; }
    else            { zt = z1t; w = w_ih1 + (size_t)row * 273 + (MELn + RHYn); acc = b_ih1[row]; dst = gi1c; }
#pragma unroll 4
    for (int i = 0; i < 128; i++) acc = fmaf(zt[i * 64 + lane], w[i], acc);
    dst[(size_t)row * 64 + lane] = acc;
}

// ---------------------------------------------------------------------------
// 64x64 tile transpose: in [R][C] -> out [C][Rout]
// ---------------------------------------------------------------------------
__device__ __forceinline__ void transpose_body(
    const float* __restrict__ in, float* __restrict__ out, int R, int C, int Rout,
    int bx, int by, float* tile)
{
    int c0 = bx * 64, r0 = by * 64;
    int t = threadIdx.x;
    int cl = t & 63, rw = t >> 6;
#pragma unroll
    for (int i = 0; i < 16; ++i) {
        int rl = rw + i * 4;
        int r = r0 + rl, c = c0 + cl;
        float v = (r < R && c < C) ? in[(size_t)r * C + c] : 0.f;
        tile[rl * 65 + cl] = v;
    }
    __syncthreads();
#pragma unroll
    for (int i = 0; i < 16; ++i) {
        int c_loc = rw + i * 4;
        int r_loc = cl;
        int oc = c0 + c_loc, orow = r0 + r_loc;
        if (oc < C && orow < R)
            out[(size_t)oc * Rout + orow] = tile[r_loc * 65 + c_loc];
    }
}

__global__ __launch_bounds__(256) void transpose4_k(
    const float* __restrict__ a, const float* __restrict__ b,
    const float* __restrict__ c, const float* __restrict__ d,
    float* __restrict__ oa, float* __restrict__ ob,
    float* __restrict__ oc, float* __restrict__ od)
{
    __shared__ float tile[64 * 65];
    const float* in; float* out;
    switch (blockIdx.z) {
        case 0: in = a; out = oa; break;
        case 1: in = b; out = ob; break;
        case 2: in = c; out = oc; break;
        default: in = d; out = od; break;
    }
    transpose_body(in, out, G3, Hd, G3, blockIdx.x, blockIdx.y, tile);
}

__global__ __launch_bounds__(256) void transpose1_k(
    const float* __restrict__ in, float* __restrict__ out, int R, int C, int Rout)
{
    __shared__ float tile[64 * 65];
    transpose_body(in, out, R, C, Rout, blockIdx.x, blockIdx.y, tile);
}

// ---------------------------------------------------------------------------
// mm3_k: 512-thread latency-optimized k-split GEMM partial.
// Tile 128 rows x 64 batch, thread = 8 rows x 2 batch (16 acc, low VGPR).
// launch_bounds(512,6) -> 24 waves/CU (2x R3's latency hiding).
// grid (tiles, slots); fused two-matrix mode via splitTile.
// ---------------------------------------------------------------------------
template<int KC>
__global__ __launch_bounds__(512, 6) void mm3_k(
    const float* __restrict__ WTa, const float* __restrict__ xa,
    const float* __restrict__ WTb, const float* __restrict__ xb,
    float* __restrict__ part, int splitTile, int partStride)
{
    __shared__ float xs[128 * 64];
    int tid = threadIdx.x;
    int tile = blockIdx.x, slot = blockIdx.y;
    const float* WT; const float* x; int tLoc;
    if (tile < splitTile) { WT = WTa; x = xa; tLoc = tile; }
    else                  { WT = WTb; x = xb; tLoc = tile - splitTile; }

    int rg = tid & 15, bg = tid >> 4;     // 16 row-groups x 8 rows; 32 b-groups x 2
    int r0 = tLoc * 128 + rg * 8;
    int b0 = bg * 2;

    float acc[8][2];
#pragma unroll
    for (int i = 0; i < 8; i++) { acc[i][0] = 0.f; acc[i][1] = 0.f; }

    for (int ph = 0; ph < KC / 128; ++ph) {
        int kp = slot * KC + ph * 128;
        __syncthreads();
        {
            const float4* src = (const float4*)(x + (size_t)kp * 64);
            float4* dst = (float4*)xs;
#pragma unroll
            for (int i = 0; i < 4; i++) dst[tid + i * 512] = src[tid + i * 512];
        }
        __syncthreads();
        const float* wp = WT + (size_t)kp * G3 + r0;
#pragma unroll 4
        for (int k = 0; k < 128; ++k) {
            float2 xv = *(const float2*)&xs[k * 64 + b0];   // 16-way LDS broadcast
            float w[8];
            *(float4*)&w[0] = *(const float4*)wp;
            *(float4*)&w[4] = *(const float4*)(wp + 4);
            wp += G3;
#pragma unroll
            for (int i = 0; i < 8; i++) {
                acc[i][0] = fmaf(w[i], xv.x, acc[i][0]);
                acc[i][1] = fmaf(w[i], xv.y, acc[i][1]);
            }
        }
    }

    size_t base = (size_t)slot * partStride + b0;
#pragma unroll
    for (int i = 0; i < 8; i++) {
        int prow = tile * 128 + rg * 8 + i;
        *(float2*)&part[base + (size_t)prow * 64] =
            make_float2(acc[i][0], acc[i][1]);
    }
}

// ---------------------------------------------------------------------------
// mm2_k: 256-thread variant with row clamping (used only for 130-row logits)
// ---------------------------------------------------------------------------
__global__ __launch_bounds__(256) void mm2_k(
    const float* __restrict__ WT, const float* __restrict__ x,
    float* __restrict__ part, int kc, int nrows, int wstride, int partStride)
{
    __shared__ float xs[128 * 64];
    int tid = threadIdx.x;
    int tile = blockIdx.x, slot = blockIdx.y;
    int rg = tid & 15, bg = tid >> 4;
    int r0 = tile * 128 + rg * 8;
    int b0 = bg * 4;
    int k0 = slot * kc;

    float acc[8][4];
#pragma unroll
    for (int i = 0; i < 8; i++)
#pragma unroll
        for (int j = 0; j < 4; j++) acc[i][j] = 0.f;

    bool fast = (r0 + 7 < nrows);
    for (int ph = 0; ph < kc / 128; ++ph) {
        int kp = k0 + ph * 128;
        __syncthreads();
        {
            const float4* src = (const float4*)(x + (size_t)kp * 64);
            float4* dst = (float4*)xs;
#pragma unroll
            for (int i = 0; i < 8; i++) dst[tid + i * 256] = src[tid + i * 256];
        }
        __syncthreads();
        for (int k = 0; k < 128; ++k) {
            float4 xv = *(const float4*)&xs[k * 64 + b0];
            const float* wrow = WT + (size_t)(kp + k) * wstride;
            float w[8];
            if (fast) {
                *(float4*)&w[0] = *(const float4*)(wrow + r0);
                *(float4*)&w[4] = *(const float4*)(wrow + r0 + 4);
            } else {
#pragma unroll
                for (int i = 0; i < 8; i++) {
                    int rc = r0 + i; if (rc > nrows - 1) rc = nrows - 1;
                    w[i] = wrow[rc];
                }
            }
#pragma unroll
            for (int i = 0; i < 8; i++) {
                acc[i][0] = fmaf(w[i], xv.x, acc[i][0]);
                acc[i][1] = fmaf(w[i], xv.y, acc[i][1]);
                acc[i][2] = fmaf(w[i], xv.z, acc[i][2]);
                acc[i][3] = fmaf(w[i], xv.w, acc[i][3]);
            }
        }
    }

    size_t base = (size_t)slot * partStride + b0;
#pragma unroll
    for (int i = 0; i < 8; i++) {
        int prow = r0 + i;
        int pc = prow < nrows ? prow : (nrows - 1);
        *(float4*)&part[base + (size_t)pc * 64] = *(float4*)acc[i];
    }
}

// ---------------------------------------------------------------------------
// rhythm epilogue: sum 16 k-slots, gate math, h'
// ---------------------------------------------------------------------------
__global__ __launch_bounds__(256) void rhy_epi(
    const float* __restrict__ part, const float* __restrict__ gi_c,
    const float* __restrict__ w_ih, const float* __restrict__ b_hh,
    const float* __restrict__ h_in, float* __restrict__ h_out,
    const int* __restrict__ fb_idx)
{
    int tid = threadIdx.x;
    int b = tid & 63, jw = tid >> 6;
    int j = blockIdx.x * 4 + jw;
    float ar = 0.f, az = 0.f, an = 0.f;
#pragma unroll
    for (int s = 0; s < 16; s++) {
        int sb = s * 393216;
        ar += part[sb + j * 64 + b];
        az += part[sb + (j + 2048) * 64 + b];
        an += part[sb + (j + 4096) * 64 + b];
    }
    int oi = fb_idx[b];
    float gir = gi_c[j * 64 + b]            + w_ih[(size_t)j * 131 + oi];
    float giz = gi_c[(j + 2048) * 64 + b]   + w_ih[(size_t)(j + 2048) * 131 + oi];
    float gin = gi_c[(j + 4096) * 64 + b]   + w_ih[(size_t)(j + 4096) * 131 + oi];
    float rg = sigf(gir + ar + b_hh[j]);
    float ug = sigf(giz + az + b_hh[j + 2048]);
    float ng = tanhf(gin + rg * (an + b_hh[j + 4096]));
    float hp = h_in[j * 64 + b];
    h_out[j * 64 + b] = (1.f - ug) * ng + ug * hp;
}

// ---------------------------------------------------------------------------
// fused rhythm logits (3 classes) + log_softmax + argmax; 1 block, 768 thr
// ---------------------------------------------------------------------------
__global__ __launch_bounds__(768) void rhy_out_k(
    const float* __restrict__ h, const float* __restrict__ wo0,
    const float* __restrict__ bo0, float* __restrict__ rlo_t, int* __restrict__ rhy_idx)
{
    __shared__ float partl[12 * 64];
    int tid = threadIdx.x, lane = tid & 63, wave = tid >> 6;
    int c = wave >> 2, chunk = wave & 3;
    const float* w = wo0 + c * Hd + chunk * 512;
    const float* hc = h + chunk * 512 * 64;
    float acc = 0.f;
#pragma unroll 4
    for (int k = 0; k < 512; k++) acc = fmaf(hc[k * 64 + lane], w[k], acc);
    partl[wave * 64 + lane] = acc;
    __syncthreads();
    if (wave == 0) {
        float l0 = partl[0 * 64 + lane] + partl[1 * 64 + lane] + partl[2 * 64 + lane] + partl[3 * 64 + lane] + bo0[0];
        float l1 = partl[4 * 64 + lane] + partl[5 * 64 + lane] + partl[6 * 64 + lane] + partl[7 * 64 + lane] + bo0[1];
        float l2 = partl[8 * 64 + lane] + partl[9 * 64 + lane] + partl[10 * 64 + lane] + partl[11 * 64 + lane] + bo0[2];
        int am; float mx;
        if (l0 >= l1 && l0 >= l2) { am = 0; mx = l0; }
        else if (l1 >= l2)        { am = 1; mx = l1; }
        else                      { am = 2; mx = l2; }
        float s = expf(l0 - mx) + expf(l1 - mx) + expf(l2 - mx);
        float ls = logf(s);
        rlo_t[lane * 3 + 0] = l0 - mx - ls;
        rlo_t[lane * 3 + 1] = l1 - mx - ls;
        rlo_t[lane * 3 + 2] = l2 - mx - ls;
        rhy_idx[lane] = am;
    }
}

// ---------------------------------------------------------------------------
// melody GRU1 epilogue: sum 16 slots + one-hot col + rank-15 corrections
// ---------------------------------------------------------------------------
__global__ __launch_bounds__(256) void mel1_epi(
    const float* __restrict__ part, const float* __restrict__ gi_c,
    const float* __restrict__ w_ih, const float* __restrict__ b_hh,
    const float* __restrict__ h_in, float* __restrict__ h_out,
    const int* __restrict__ mel_idx, const float* __restrict__ rlo,
    const float* __restrict__ cdt)
{
    int tid = threadIdx.x;
    int b = tid & 63, jw = tid >> 6;
    int j = blockIdx.x * 4 + jw;
    float ar = 0.f, az = 0.f, an = 0.f;
#pragma unroll
    for (int s = 0; s < 16; s++) {
        int sb = s * 393216;
        ar += part[sb + j * 64 + b];
        az += part[sb + (j + 2048) * 64 + b];
        an += part[sb + (j + 4096) * 64 + b];
    }
    int oi = mel_idx[b];
    float r0 = rlo[b * 3 + 0], r1 = rlo[b * 3 + 1], r2 = rlo[b * 3 + 2];
    float cd[12];
#pragma unroll
    for (int q = 0; q < 12; q++) cd[q] = cdt[q * 64 + b];
    float gi[3];
#pragma unroll
    for (int g = 0; g < 3; g++) {
        int row = j + g * 2048;
        const float* wrow = w_ih + (size_t)row * 273;
        float v = gi_c[row * 64 + b] + wrow[oi];
        v = fmaf(r0, wrow[130], v);
        v = fmaf(r1, wrow[131], v);
        v = fmaf(r2, wrow[132], v);
#pragma unroll
        for (int q = 0; q < 12; q++) v = fmaf(cd[q], wrow[261 + q], v);
        gi[g] = v;
    }
    float rg = sigf(gi[0] + ar + b_hh[j]);
    float ug = sigf(gi[1] + az + b_hh[j + 2048]);
    float ng = tanhf(gi[2] + rg * (an + b_hh[j + 4096]));
    float hp = h_in[j * 64 + b];
    h_out[j * 64 + b] = (1.f - ug) * ng + ug * hp;
}

// ---------------------------------------------------------------------------
// melody GRU2 epilogue: fused rows [0,6144)=gi (ih2 x ha'), [6144,12288)=gh
// ---------------------------------------------------------------------------
__global__ __launch_bounds__(256) void mel2_epi(
    const float* __restrict__ part, const float* __restrict__ b_ih,
    const float* __restrict__ b_hh, const float* __restrict__ hb_in,
    float* __restrict__ hb_out)
{
    int tid = threadIdx.x;
    int b = tid & 63, jw = tid >> 6;
    int j = blockIdx.x * 4 + jw;
    float air = 0.f, aiz = 0.f, ain = 0.f, ahr = 0.f, ahz = 0.f, ahn = 0.f;
#pragma unroll
    for (int s = 0; s < 8; s++) {
        int sb = s * 786432;
        air += part[sb + j * 64 + b];
        aiz += part[sb + (j + 2048) * 64 + b];
        ain += part[sb + (j + 4096) * 64 + b];
        ahr += part[sb + (j + 6144) * 64 + b];
        ahz += part[sb + (j + 8192) * 64 + b];
        ahn += part[sb + (j + 10240) * 64 + b];
    }
    float rg = sigf(air + b_ih[j] + ahr + b_hh[j]);
    float ug = sigf(aiz + b_ih[j + 2048] + ahz + b_hh[j + 2048]);
    float ng = tanhf(ain + b_ih[j + 4096] + rg * (ahn + b_hh[j + 4096]));
    float hp = hb_in[j * 64 + b];
    hb_out[j * 64 + b] = (1.f - ug) * ng + ug * hp;
}

// ---------------------------------------------------------------------------
// melody softmax: 130 classes from 16 partial slots (stride 8320), argmax fb
// ---------------------------------------------------------------------------
__global__ __launch_bounds__(256) void mel_smax(
    const float* __restrict__ part, const float* __restrict__ bo1,
    float* __restrict__ outp, int t, int* __restrict__ mel_idx)
{
    int b = blockIdx.x, tid = threadIdx.x;
    float v = -1e30f;
    if (tid < MELn) {
        v = bo1[tid];
#pragma unroll
        for (int s = 0; s < 16; s++) v += part[s * 8320 + tid * 64 + b];
    }
    __shared__ float smax[256];
    __shared__ int   sidx[256];
    __shared__ float ssum[256];
    smax[tid] = v; sidx[tid] = tid;
    __syncthreads();
    for (int s = 128; s > 0; s >>= 1) {
        if (tid < s) {
            float a = smax[tid], o = smax[tid + s];
            int ai = sidx[tid], oi = sidx[tid + s];
            if (o > a || (o == a && oi < ai)) { smax[tid] = o; sidx[tid] = oi; }
        }
        __syncthreads();
    }
    float mx = smax[0]; int am = sidx[0];
    ssum[tid] = (tid < MELn) ? expf(v - mx) : 0.f;
    __syncthreads();
    for (int s = 128; s > 0; s >>= 1) {
        if (tid < s) ssum[tid] += ssum[tid + s];
        __syncthreads();
    }
    float ls = logf(ssum[0]);
    if (tid < MELn) outp[(size_t)b * Tn * MELn + t * MELn + tid] = v - mx - ls;
    if (tid == 0) mel_idx[b] = am;
}

// ---------------------------------------------------------------------------
extern "C" void kernel_launch(void* const* d_in, const int* in_sizes, int n_in,
                              void* d_out, int out_size, void* d_ws, size_t ws_size,
                              hipStream_t stream)
{
    (void)in_sizes; (void)n_in; (void)out_size; (void)ws_size;
    const float* z1    = (const float*)d_in[0];
    const float* z2    = (const float*)d_in[1];
    const float* cond  = (const float*)d_in[2];
    const float* w_ih0 = (const float*)d_in[3];
    const float* w_hh0 = (const float*)d_in[4];
    const float* b_ih0 = (const float*)d_in[5];
    const float* b_hh0 = (const float*)d_in[6];
    const float* w_ih1 = (const float*)d_in[7];
    const float* w_hh1 = (const float*)d_in[8];
    const float* b_ih1 = (const float*)d_in[9];
    const float* b_hh1 = (const float*)d_in[10];
    const float* w_ih2 = (const float*)d_in[11];
    const float* w_hh2 = (const float*)d_in[12];
    const float* b_ih2 = (const float*)d_in[13];
    const float* b_hh2 = (const float*)d_in[14];
    const float* wi0   = (const float*)d_in[15];
    const float* bi0   = (const float*)d_in[16];
    const float* wo0   = (const float*)d_in[17];
    const float* bo0   = (const float*)d_in[18];
    const float* wi1   = (const float*)d_in[19];
    const float* bi1   = (const float*)d_in[20];
    const float* wo1   = (const float*)d_in[21];
    const float* bo1   = (const float*)d_in[22];
    float* outp = (float*)d_out;
    float* ws = (float*)d_ws;

    // workspace layout (floats), ~232 MB
    size_t off = 0;
    float* WT0  = ws + off; off += 12582912;   // w_hh0^T [2048][6144]
    float* WT1  = ws + off; off += 12582912;   // w_hh1^T
    float* WTi2 = ws + off; off += 12582912;   // w_ih2^T
    float* WTh2 = ws + off; off += 12582912;   // w_hh2^T
    float* WTo1 = ws + off; off += 270336;     // wo1^T [2048][132]
    float* part = ws + off; off += 6291456;    // k-split partials (25 MB)
    float* hR[2] = { ws + off, ws + off + 131072 }; off += 262144;
    float* hA[2] = { ws + off, ws + off + 131072 }; off += 262144;
    float* hB[2] = { ws + off, ws + off + 131072 }; off += 262144;
    float* gi0c   = ws + off; off += 393216;
    float* gi1c   = ws + off; off += 393216;
    float* rlo    = ws + off; off += 6144;     // [32][64][3]
    float* cond_t = ws + off; off += 24576;
    float* z1t    = ws + off; off += 8192;
    float* z2t    = ws + off; off += 8192;
    int* rhy_idx  = (int*)(ws + off); off += 64;
    int* mel_idx  = (int*)(ws + off); off += 64;

    // ---- pre-pass ----
    prep_misc<<<96, 256, 0, stream>>>(z1, z2, cond, z1t, z2t, cond_t, rhy_idx, mel_idx);
    init_h_k<<<dim3(Hd / 4, 2), 256, 0, stream>>>(z1t, z2t, wi0, bi0, wi1, bi1, hR[0], hA[0]);
    gi_const_k<<<dim3(G3 / 4, 2), 256, 0, stream>>>(z1t, z2t, w_ih0, b_ih0, w_ih1, b_ih1, gi0c, gi1c);
    transpose4_k<<<dim3(32, 96, 4), 256, 0, stream>>>(w_hh0, w_hh1, w_ih2, w_hh2,
                                                      WT0, WT1, WTi2, WTh2);
    transpose1_k<<<dim3(32, 3), 256, 0, stream>>>(wo1, WTo1, MELn, Hd, 132);

    // ---- rhythm decoder ----
    for (int s = 0; s < Tn; s++) {
        const float* h_in = hR[s & 1];
        float* h_out = hR[(s + 1) & 1];
        mm3_k<128><<<dim3(48, 16), 512, 0, stream>>>(WT0, h_in, WT0, h_in, part,
                                                     48, 393216);
        rhy_epi<<<512, 256, 0, stream>>>(part, gi0c, w_ih0, b_hh0, h_in, h_out, rhy_idx);
        rhy_out_k<<<1, 768, 0, stream>>>(h_out, wo0, bo0, rlo + s * 192, rhy_idx);
    }

    // ---- melody decoder ----
    for (int t = 0; t < Tn; t++) {
        const float* ha_in = hA[t & 1];
        float* ha_out = hA[(t + 1) & 1];
        mm3_k<128><<<dim3(48, 16), 512, 0, stream>>>(WT1, ha_in, WT1, ha_in, part,
                                                     48, 393216);
        mel1_epi<<<512, 256, 0, stream>>>(part, gi1c, w_ih1, b_hh1, ha_in, ha_out,
                                          mel_idx, rlo + t * 192, cond_t + t * (CHn * Bsz));
        const float* hb_in = (t == 0) ? (const float*)ha_out : (const float*)hB[t & 1];
        float* hb_out = hB[(t + 1) & 1];
        mm3_k<256><<<dim3(96, 8), 512, 0, stream>>>(WTi2, ha_out, WTh2, hb_in, part,
                                                    48, 786432);
        mel2_epi<<<512, 256, 0, stream>>>(part, b_ih2, b_hh2, hb_in, hb_out);
        mm2_k<<<dim3(2, 16), 256, 0, stream>>>(WTo1, hb_out, part, 128, MELn, 132, 8320);
        mel_smax<<<Bsz, 256, 0, stream>>>(part, bo1, outp, t, mel_idx);
    }
}